// Round 5
// baseline (4577.354 us; speedup 1.0000x reference)
//
#include <hip/hip_runtime.h>
#include <hip/hip_bf16.h>
#include <cstddef>

#define BATCH 16
#define TSTEPS 128
#define MSLOTS 512
#define DIN 256
#define UNITS 256
#define ZDIM 1024
#define G 8          // blocks per batch
#define NBLK (BATCH*G)
#define NTHR 512

static __device__ __forceinline__ float tanhf_fast(float x) {
    float e = __expf(2.0f * x);
    return 1.0f - 2.0f / (e + 1.0f);
}
static __device__ __forceinline__ float sigmoidf_fast(float x) {
    return 1.0f / (1.0f + __expf(-x));
}
static __device__ __forceinline__ void st_agent(float* p, float v) {
    __hip_atomic_store(p, v, __ATOMIC_RELAXED, __HIP_MEMORY_SCOPE_AGENT);
}
static __device__ __forceinline__ float ld_agent(const float* p) {
    return __hip_atomic_load(p, __ATOMIC_RELAXED, __HIP_MEMORY_SCOPE_AGENT);
}
static __device__ __forceinline__ unsigned ld_agent_u(const unsigned* p) {
    return __hip_atomic_load(p, __ATOMIC_RELAXED, __HIP_MEMORY_SCOPE_AGENT);
}
// pack two f32 -> bf16 pair (rne); lo = a, hi = b
static __device__ __forceinline__ unsigned pack_bf(float a, float b) {
    unsigned ua = __float_as_uint(a); ua = (ua + 0x7fffu + ((ua >> 16) & 1u)) >> 16;
    unsigned ub = __float_as_uint(b); ub = ((ub + 0x7fffu + ((ub >> 16) & 1u)) >> 16) << 16;
    return ua | ub;
}
static __device__ __forceinline__ float bf_lo(unsigned w) { return __uint_as_float(w << 16); }
static __device__ __forceinline__ float bf_hi(unsigned w) { return __uint_as_float(w & 0xffff0000u); }

// ---------------------------------------------------------------------------
// f32 GEMM + bias: C[M][N] = A @ B + bias. 64x64 tile, 256 thr, 4x4/thread.
// ---------------------------------------------------------------------------
__global__ __launch_bounds__(256) void gemm_bias_kernel(
    const float* __restrict__ A, const float* __restrict__ B,
    const float* __restrict__ bias, float* __restrict__ C,
    int M, int N, int K)
{
    __shared__ float As[16][68];
    __shared__ float Bs[16][68];
    const int tid = threadIdx.x;
    const int bm = blockIdx.x * 64;
    const int bn = blockIdx.y * 64;
    const int tx = tid & 15, ty = tid >> 4;
    const int ar = tid >> 2, ac = (tid & 3) * 4;
    const int br = tid >> 4, bc = (tid & 15) * 4;
    float acc[4][4] = {};

    for (int k0 = 0; k0 < K; k0 += 16) {
        float4 av = *(const float4*)(A + (size_t)(bm + ar) * K + k0 + ac);
        float4 bv = *(const float4*)(B + (size_t)(k0 + br) * N + bn + bc);
        As[ac + 0][ar] = av.x; As[ac + 1][ar] = av.y;
        As[ac + 2][ar] = av.z; As[ac + 3][ar] = av.w;
        *(float4*)(&Bs[br][bc]) = bv;
        __syncthreads();
#pragma unroll
        for (int kk = 0; kk < 16; ++kk) {
            float a0 = As[kk][ty*4+0], a1 = As[kk][ty*4+1];
            float a2 = As[kk][ty*4+2], a3 = As[kk][ty*4+3];
            float b0 = Bs[kk][tx*4+0], b1 = Bs[kk][tx*4+1];
            float b2 = Bs[kk][tx*4+2], b3 = Bs[kk][tx*4+3];
            acc[0][0]+=a0*b0; acc[0][1]+=a0*b1; acc[0][2]+=a0*b2; acc[0][3]+=a0*b3;
            acc[1][0]+=a1*b0; acc[1][1]+=a1*b1; acc[1][2]+=a1*b2; acc[1][3]+=a1*b3;
            acc[2][0]+=a2*b0; acc[2][1]+=a2*b1; acc[2][2]+=a2*b2; acc[2][3]+=a2*b3;
            acc[3][0]+=a3*b0; acc[3][1]+=a3*b1; acc[3][2]+=a3*b2; acc[3][3]+=a3*b3;
        }
        __syncthreads();
    }
#pragma unroll
    for (int i = 0; i < 4; ++i)
#pragma unroll
        for (int j = 0; j < 4; ++j) {
            int cn = bn + tx * 4 + j;
            C[(size_t)(bm + ty * 4 + i) * N + cn] = acc[i][j] + bias[cn];
        }
}

// ---------------------------------------------------------------------------
// GEMM, no bias, bf16 output, per-batch TRANSPOSED store: CT[b][n][m] ushort.
// A rows are batch-major (512 rows per batch). Used for AW2 = attended @ W2.
// ---------------------------------------------------------------------------
__global__ __launch_bounds__(256) void gemm_T_bf16_kernel(
    const float* __restrict__ A, const float* __restrict__ B,
    unsigned short* __restrict__ CT, int M, int N, int K)
{
    __shared__ float As[16][68];
    __shared__ float Bs[16][68];
    __shared__ float Ts[64][65];
    const int tid = threadIdx.x;
    const int bm = blockIdx.x * 64;
    const int bn = blockIdx.y * 64;
    const int tx = tid & 15, ty = tid >> 4;
    const int ar = tid >> 2, ac = (tid & 3) * 4;
    const int br = tid >> 4, bc = (tid & 15) * 4;
    float acc[4][4] = {};

    for (int k0 = 0; k0 < K; k0 += 16) {
        float4 av = *(const float4*)(A + (size_t)(bm + ar) * K + k0 + ac);
        float4 bv = *(const float4*)(B + (size_t)(k0 + br) * N + bn + bc);
        As[ac + 0][ar] = av.x; As[ac + 1][ar] = av.y;
        As[ac + 2][ar] = av.z; As[ac + 3][ar] = av.w;
        *(float4*)(&Bs[br][bc]) = bv;
        __syncthreads();
#pragma unroll
        for (int kk = 0; kk < 16; ++kk) {
            float a0 = As[kk][ty*4+0], a1 = As[kk][ty*4+1];
            float a2 = As[kk][ty*4+2], a3 = As[kk][ty*4+3];
            float b0 = Bs[kk][tx*4+0], b1 = Bs[kk][tx*4+1];
            float b2 = Bs[kk][tx*4+2], b3 = Bs[kk][tx*4+3];
            acc[0][0]+=a0*b0; acc[0][1]+=a0*b1; acc[0][2]+=a0*b2; acc[0][3]+=a0*b3;
            acc[1][0]+=a1*b0; acc[1][1]+=a1*b1; acc[1][2]+=a1*b2; acc[1][3]+=a1*b3;
            acc[2][0]+=a2*b0; acc[2][1]+=a2*b1; acc[2][2]+=a2*b2; acc[2][3]+=a2*b3;
            acc[3][0]+=a3*b0; acc[3][1]+=a3*b1; acc[3][2]+=a3*b2; acc[3][3]+=a3*b3;
        }
        __syncthreads();
    }
#pragma unroll
    for (int i = 0; i < 4; ++i)
#pragma unroll
        for (int j = 0; j < 4; ++j)
            Ts[tx * 4 + j][ty * 4 + i] = acc[i][j];
    __syncthreads();
    const int jr = tid >> 2, ms2 = (tid & 3) * 16;
    const int b = bm >> 9, m0 = bm & 511;
    unsigned short* dst = CT + (size_t)b * ((size_t)N * 512)
                        + (size_t)(bn + jr) * 512 + m0 + ms2;
#pragma unroll
    for (int u = 0; u < 16; ++u) {
        unsigned ua = __float_as_uint(Ts[jr][ms2 + u]);
        ua = (ua + 0x7fffu + ((ua >> 16) & 1u)) >> 16;
        dst[u] = (unsigned short)ua;
    }
}

// ---------------------------------------------------------------------------
// Persistent scan: 128 blocks (8 per batch, XCD-clustered), 512 threads.
// Fence-free sync: relaxed bypass atomics only; __syncthreads() drains vmcnt
// before each flag store; publishes confined to wave 0. Two barriers/step,
// payloads 260B (p,denom) and 128B (h-slice) per block.
// col c of block g (cc in [0,128)): col = (cc>>5)*256 + g*32 + (cc&31).
// ---------------------------------------------------------------------------
__global__ __launch_bounds__(NTHR, 2) void rnn_persistent(
    const float* __restrict__ query_W, const float* __restrict__ query_b,
    const float* __restrict__ attn_W,  const float* __restrict__ lstm_U,
    const float* __restrict__ keys,    const float* __restrict__ pre,
    const unsigned short* __restrict__ aw2T,
    float* pB, float* dB, float* hB, unsigned* flags,
    float* __restrict__ seq, float* __restrict__ hT, float* __restrict__ cT)
{
    const int bid = blockIdx.x;
    // XCD clustering heuristic (perf only): a batch's 8 blocks share bid%8
    const int b = (bid & 7) * 2 + (bid >> 6);
    const int g = (bid >> 3) & 7;
    const int tid = threadIdx.x;

    __shared__ __align__(16) float h_s[256];
    __shared__ __align__(16) float q_s[256];
    __shared__ __align__(16) float qp_s[8][256];
    __shared__ __align__(16) float aw_s[256];
    __shared__ __align__(16) float qb_s[256];
    __shared__ __align__(16) float pown_s[64];
    __shared__ __align__(16) float pgat_s[512];
    __shared__ __align__(16) float zp_s[8][128];
    __shared__ __align__(16) float z_s[128];
    __shared__ float invd_s;

    // roles
    const int c64 = tid & 63, ms = tid >> 6;      // z-phase: 2 cols, m/k-slice ms
    const int j4  = tid & 63, kh = tid >> 6;      // q-phase: 4 cols, k-block kh
    const int mloc = tid >> 3, pp = tid & 7;      // scores: own m, j-octant pp

    const int cc0 = 2 * c64, cc1 = 2 * c64 + 1;
    const int col0 = ((cc0 >> 5) << 8) + g * 32 + (cc0 & 31);
    const int col1 = ((cc1 >> 5) << 8) + g * 32 + (cc1 & 31);

    // ---- t-invariant register state ----
    unsigned wq_r[4][16];    // Wq[kh*32+2i(+1)][j4*4+cc] bf16 pairs (pack along k)
#pragma unroll
    for (int cci = 0; cci < 4; ++cci) {
        int j = j4 * 4 + cci;
#pragma unroll
        for (int i = 0; i < 16; ++i)
            wq_r[cci][i] = pack_bf(query_W[(size_t)(kh * 32 + 2 * i) * 256 + j],
                                   query_W[(size_t)(kh * 32 + 2 * i + 1) * 256 + j]);
    }
    unsigned keys_r[16];     // keys[b][g*64+mloc][pp*32 + 2*jp(+1)], pre-rotated
    {
        const float* krow = keys + ((size_t)(b * MSLOTS + g * 64 + mloc)) * 256 + pp * 32;
#pragma unroll
        for (int i = 0; i < 16; ++i) {
            int jp = (i + pp * 2) & 15;
            keys_r[i] = pack_bf(krow[jp * 2], krow[jp * 2 + 1]);
        }
    }
    unsigned u_r[2][16];     // U[ms*32+2j(+1)][col] bf16 pairs (pack along k)
#pragma unroll
    for (int j = 0; j < 16; ++j) {
        u_r[0][j] = pack_bf(lstm_U[(size_t)(ms * 32 + 2 * j) * ZDIM + col0],
                            lstm_U[(size_t)(ms * 32 + 2 * j + 1) * ZDIM + col0]);
        u_r[1][j] = pack_bf(lstm_U[(size_t)(ms * 32 + 2 * j) * ZDIM + col1],
                            lstm_U[(size_t)(ms * 32 + 2 * j + 1) * ZDIM + col1]);
    }
    unsigned aw2_r[2][32];   // AW2[m = ms*64 + 2j(+1)][col] bf16 pairs (along m)
    {
        const unsigned* a0 = (const unsigned*)(aw2T + ((size_t)b * ZDIM + col0) * 512 + ms * 64);
        const unsigned* a1 = (const unsigned*)(aw2T + ((size_t)b * ZDIM + col1) * 512 + ms * 64);
#pragma unroll
        for (int j = 0; j < 32; ++j) { aw2_r[0][j] = a0[j]; aw2_r[1][j] = a1[j]; }
    }

    if (tid < 256) { aw_s[tid] = attn_W[tid]; qb_s[tid] = query_b[tid]; h_s[tid] = 0.0f; }
    float c_r = 0.0f;   // cell state for unit g*32 + tid (tid<32)
    __syncthreads();

    const float* preb = pre + (size_t)b * TSTEPS * ZDIM;
    unsigned* fl = flags + b * 16;

    for (int t = 0; t < TSTEPS; ++t) {
        // hoisted pre load for this thread's z-reduce role (tid<128)
        float pre_r = 0.0f;
        if (tid < 128)
            pre_r = preb[(size_t)t * ZDIM + ((tid >> 5) << 8) + g * 32 + (tid & 31)];

        // ---- phase Q: q = h @ Wq + qb (redundant per block, from registers) ----
        {
            float qa0 = 0.f, qa1 = 0.f, qa2 = 0.f, qa3 = 0.f;
#pragma unroll
            for (int i = 0; i < 16; ++i) {
                float2 hv = *(const float2*)&h_s[kh * 32 + 2 * i];
                unsigned w0 = wq_r[0][i], w1 = wq_r[1][i], w2 = wq_r[2][i], w3 = wq_r[3][i];
                qa0 += hv.x * bf_lo(w0) + hv.y * bf_hi(w0);
                qa1 += hv.x * bf_lo(w1) + hv.y * bf_hi(w1);
                qa2 += hv.x * bf_lo(w2) + hv.y * bf_hi(w2);
                qa3 += hv.x * bf_lo(w3) + hv.y * bf_hi(w3);
            }
            *(float4*)&qp_s[kh][j4 * 4] = make_float4(qa0, qa1, qa2, qa3);
        }
        __syncthreads();
        if (tid < 256) {
            float acc = qb_s[tid];
#pragma unroll
            for (int i = 0; i < 8; ++i) acc += qp_s[i][tid];
            q_s[tid] = acc;
        }
        __syncthreads();

        // ---- phase S: scores + exp for own 64 m (keys in registers) ----
        {
            float sacc = 0.0f;
#pragma unroll
            for (int i = 0; i < 16; ++i) {
                int jp = (i + pp * 2) & 15;
                int j = pp * 32 + jp * 2;
                float2 qv = *(const float2*)&q_s[j];
                float2 av = *(const float2*)&aw_s[j];
                unsigned kw = keys_r[i];
                sacc += av.x * tanhf_fast(bf_lo(kw) + qv.x);
                sacc += av.y * tanhf_fast(bf_hi(kw) + qv.y);
            }
            sacc += __shfl_xor(sacc, 1);
            sacc += __shfl_xor(sacc, 2);
            sacc += __shfl_xor(sacc, 4);
            if (pp == 0) pown_s[mloc] = __expf(sacc);   // |s| <= ~13, no max-sub
        }
        __syncthreads();
        // publish p (own 64 m) + denom partial — wave 0 only
        if (tid < 64) {
            float v = pown_s[tid];
            st_agent(&pB[b * 512 + g * 64 + tid], v);
            v += __shfl_xor(v, 1);  v += __shfl_xor(v, 2);  v += __shfl_xor(v, 4);
            v += __shfl_xor(v, 8);  v += __shfl_xor(v, 16); v += __shfl_xor(v, 32);
            if (tid == 0) st_agent(&dB[b * 8 + g], v);
        }

        // ---- barrier 1 (fence-free): syncthreads drains vmcnt before flag ----
        __syncthreads();
        if (tid == 0) {
            asm volatile("s_waitcnt vmcnt(0)" ::: "memory");
            __hip_atomic_store(&fl[g], (unsigned)(2 * t + 1), __ATOMIC_RELAXED,
                               __HIP_MEMORY_SCOPE_AGENT);
        }
        if (tid < G) {
            while (ld_agent_u(&fl[tid]) < (unsigned)(2 * t + 1))
                __builtin_amdgcn_s_sleep(2);
        }
        __syncthreads();
        asm volatile("" ::: "memory");

        // ---- gather p + denom ----
        pgat_s[tid] = ld_agent(&pB[b * 512 + tid]);
        if (tid < 8) {
            float dv = ld_agent(&dB[b * 8 + tid]);
            dv += __shfl_xor(dv, 1); dv += __shfl_xor(dv, 2); dv += __shfl_xor(dv, 4);
            if (tid == 0) invd_s = 1.0f / dv;
        }
        __syncthreads();

        // ---- phase Z: own 2 cols from registers ----
        {
            float zc0 = 0.f, zc1 = 0.f;
#pragma unroll
            for (int i = 0; i < 16; ++i) {
                float4 pv = *(const float4*)&pgat_s[ms * 64 + i * 4];
                unsigned w00 = aw2_r[0][2*i], w01 = aw2_r[0][2*i+1];
                unsigned w10 = aw2_r[1][2*i], w11 = aw2_r[1][2*i+1];
                zc0 += pv.x*bf_lo(w00) + pv.y*bf_hi(w00) + pv.z*bf_lo(w01) + pv.w*bf_hi(w01);
                zc1 += pv.x*bf_lo(w10) + pv.y*bf_hi(w10) + pv.z*bf_lo(w11) + pv.w*bf_hi(w11);
            }
            float zh0 = 0.f, zh1 = 0.f;
#pragma unroll
            for (int i = 0; i < 8; ++i) {
                float4 hv = *(const float4*)&h_s[ms * 32 + i * 4];
                unsigned w00 = u_r[0][2*i], w01 = u_r[0][2*i+1];
                unsigned w10 = u_r[1][2*i], w11 = u_r[1][2*i+1];
                zh0 += hv.x*bf_lo(w00) + hv.y*bf_hi(w00) + hv.z*bf_lo(w01) + hv.w*bf_hi(w01);
                zh1 += hv.x*bf_lo(w10) + hv.y*bf_hi(w10) + hv.z*bf_lo(w11) + hv.w*bf_hi(w11);
            }
            float inv = invd_s;
            *(float2*)&zp_s[ms][c64 * 2] = make_float2(zc0 * inv + zh0, zc1 * inv + zh1);
        }
        __syncthreads();
        if (tid < 128) {
            float z = pre_r;
#pragma unroll
            for (int i = 0; i < 8; ++i) z += zp_s[i][tid];
            z_s[tid] = z;
        }
        __syncthreads();

        // ---- gates + state for own 32 units; publish h-slice (wave 0) ----
        if (tid < 32) {
            float zi = z_s[tid], zf = z_s[32 + tid], zg = z_s[64 + tid], zo = z_s[96 + tid];
            float ig = sigmoidf_fast(zi);
            float fg = sigmoidf_fast(zf);
            float gg = tanhf_fast(zg);
            float og = sigmoidf_fast(zo);
            float cn = fg * c_r + ig * gg;
            float hn = og * tanhf_fast(cn);
            c_r = cn;
            int u = g * 32 + tid;
            st_agent(&hB[b * 256 + u], hn);
            seq[((size_t)b * TSTEPS + t) * UNITS + u] = hn;
            if (t == TSTEPS - 1) { hT[b * UNITS + u] = hn; cT[b * UNITS + u] = cn; }
        }

        // ---- barrier 2 ----
        __syncthreads();
        if (tid == 0) {
            asm volatile("s_waitcnt vmcnt(0)" ::: "memory");
            __hip_atomic_store(&fl[g], (unsigned)(2 * t + 2), __ATOMIC_RELAXED,
                               __HIP_MEMORY_SCOPE_AGENT);
        }
        if (tid < G) {
            while (ld_agent_u(&fl[tid]) < (unsigned)(2 * t + 2))
                __builtin_amdgcn_s_sleep(2);
        }
        __syncthreads();
        asm volatile("" ::: "memory");

        // ---- gather full h ----
        if (tid < 256)
            h_s[tid] = ld_agent(&hB[b * 256 + tid]);
        __syncthreads();
    }
}

// ---------------------------------------------------------------------------
extern "C" void kernel_launch(void* const* d_in, const int* in_sizes, int n_in,
                              void* d_out, int out_size, void* d_ws, size_t ws_size,
                              hipStream_t stream)
{
    (void)in_sizes; (void)n_in; (void)out_size; (void)ws_size;
    const float* inputs   = (const float*)d_in[0];
    const float* attended = (const float*)d_in[1];
    const float* key_W    = (const float*)d_in[2];
    const float* key_b    = (const float*)d_in[3];
    const float* query_W  = (const float*)d_in[4];
    const float* query_b  = (const float*)d_in[5];
    const float* attn_W   = (const float*)d_in[6];
    const float* lstm_W   = (const float*)d_in[8];
    const float* lstm_U   = (const float*)d_in[9];
    const float* lstm_b   = (const float*)d_in[10];
    // attn_b (d_in[7]) cancels in softmax — dropped.

    float* out = (float*)d_out;
    float* seq = out;
    float* hT  = out + (size_t)BATCH * TSTEPS * UNITS;
    float* cT  = hT + BATCH * UNITS;

    float* ws = (float*)d_ws;
    float* keys = ws;                                        // 2,097,152 f
    float* pre  = keys + 2097152;                            // 2,097,152 f
    unsigned short* aw2T = (unsigned short*)(pre + 2097152); // 16*1024*512 ushort
    float* pB = (float*)(aw2T + (size_t)16 * 1024 * 512);    // 8192 f
    float* dB = pB + 8192;                                   // 128 f
    float* hB = dB + 128;                                    // 4096 f
    unsigned* flags = (unsigned*)(hB + 4096);                // 256 u32

    hipMemsetAsync(flags, 0, BATCH * 16 * sizeof(unsigned), stream);

    // keys = attended @ key_W + key_b          (8192 x 256)
    gemm_bias_kernel<<<dim3(128, 4), 256, 0, stream>>>(
        attended, key_W, key_b, keys, 8192, 256, 256);
    // pre = inputs @ lstm_W[:256] + lstm_b     (2048 x 1024)
    gemm_bias_kernel<<<dim3(32, 16), 256, 0, stream>>>(
        inputs, lstm_W, lstm_b, pre, 2048, 1024, 256);
    // AW2^T (bf16) = (attended @ lstm_W[256:])^T per batch: [b][1024][512]
    gemm_T_bf16_kernel<<<dim3(128, 16), 256, 0, stream>>>(
        attended, lstm_W + (size_t)256 * ZDIM, aw2T, 8192, 1024, 256);

    rnn_persistent<<<dim3(NBLK), dim3(NTHR), 0, stream>>>(
        query_W, query_b, attn_W, lstm_U,
        keys, pre, aw2T, pB, dB, hB, flags, seq, hT, cT);
}

// Round 6
// 3808.418 us; speedup vs baseline: 1.2019x; 1.2019x over previous
//
#include <hip/hip_runtime.h>
#include <hip/hip_bf16.h>
#include <cstddef>

#define BATCH 16
#define TSTEPS 128
#define MSLOTS 512
#define DIN 256
#define UNITS 256
#define ZDIM 1024
#define G 8          // blocks per batch
#define NBLK (BATCH*G)
#define NTHR 512

static __device__ __forceinline__ float tanhf_fast(float x) {
    float e = __expf(2.0f * x);
    return 1.0f - 2.0f / (e + 1.0f);
}
static __device__ __forceinline__ float sigmoidf_fast(float x) {
    return 1.0f / (1.0f + __expf(-x));
}
static __device__ __forceinline__ void st_agent_u(unsigned* p, unsigned v) {
    __hip_atomic_store(p, v, __ATOMIC_RELAXED, __HIP_MEMORY_SCOPE_AGENT);
}
static __device__ __forceinline__ unsigned ld_agent_u(const unsigned* p) {
    return __hip_atomic_load(p, __ATOMIC_RELAXED, __HIP_MEMORY_SCOPE_AGENT);
}
// Poll a tagged word until its low byte == tag; return value with tag cleared.
static __device__ __forceinline__ float poll_tagged(const unsigned* p, unsigned tag) {
    unsigned w = ld_agent_u(p);
    while ((w & 0xFFu) != tag) {
        __builtin_amdgcn_s_sleep(1);
        w = ld_agent_u(p);
    }
    return __uint_as_float(w & 0xFFFFFF00u);
}
// pack two f32 -> bf16 pair (rne); lo = a, hi = b
static __device__ __forceinline__ unsigned pack_bf(float a, float b) {
    unsigned ua = __float_as_uint(a); ua = (ua + 0x7fffu + ((ua >> 16) & 1u)) >> 16;
    unsigned ub = __float_as_uint(b); ub = ((ub + 0x7fffu + ((ub >> 16) & 1u)) >> 16) << 16;
    return ua | ub;
}
static __device__ __forceinline__ float bf_lo(unsigned w) { return __uint_as_float(w << 16); }
static __device__ __forceinline__ float bf_hi(unsigned w) { return __uint_as_float(w & 0xffff0000u); }

// ---------------------------------------------------------------------------
// f32 GEMM + bias: C[M][N] = A @ B + bias. 64x64 tile, 256 thr, 4x4/thread.
// ---------------------------------------------------------------------------
__global__ __launch_bounds__(256) void gemm_bias_kernel(
    const float* __restrict__ A, const float* __restrict__ B,
    const float* __restrict__ bias, float* __restrict__ C,
    int M, int N, int K)
{
    __shared__ float As[16][68];
    __shared__ float Bs[16][68];
    const int tid = threadIdx.x;
    const int bm = blockIdx.x * 64;
    const int bn = blockIdx.y * 64;
    const int tx = tid & 15, ty = tid >> 4;
    const int ar = tid >> 2, ac = (tid & 3) * 4;
    const int br = tid >> 4, bc = (tid & 15) * 4;
    float acc[4][4] = {};

    for (int k0 = 0; k0 < K; k0 += 16) {
        float4 av = *(const float4*)(A + (size_t)(bm + ar) * K + k0 + ac);
        float4 bv = *(const float4*)(B + (size_t)(k0 + br) * N + bn + bc);
        As[ac + 0][ar] = av.x; As[ac + 1][ar] = av.y;
        As[ac + 2][ar] = av.z; As[ac + 3][ar] = av.w;
        *(float4*)(&Bs[br][bc]) = bv;
        __syncthreads();
#pragma unroll
        for (int kk = 0; kk < 16; ++kk) {
            float a0 = As[kk][ty*4+0], a1 = As[kk][ty*4+1];
            float a2 = As[kk][ty*4+2], a3 = As[kk][ty*4+3];
            float b0 = Bs[kk][tx*4+0], b1 = Bs[kk][tx*4+1];
            float b2 = Bs[kk][tx*4+2], b3 = Bs[kk][tx*4+3];
            acc[0][0]+=a0*b0; acc[0][1]+=a0*b1; acc[0][2]+=a0*b2; acc[0][3]+=a0*b3;
            acc[1][0]+=a1*b0; acc[1][1]+=a1*b1; acc[1][2]+=a1*b2; acc[1][3]+=a1*b3;
            acc[2][0]+=a2*b0; acc[2][1]+=a2*b1; acc[2][2]+=a2*b2; acc[2][3]+=a2*b3;
            acc[3][0]+=a3*b0; acc[3][1]+=a3*b1; acc[3][2]+=a3*b2; acc[3][3]+=a3*b3;
        }
        __syncthreads();
    }
#pragma unroll
    for (int i = 0; i < 4; ++i)
#pragma unroll
        for (int j = 0; j < 4; ++j) {
            int cn = bn + tx * 4 + j;
            C[(size_t)(bm + ty * 4 + i) * N + cn] = acc[i][j] + bias[cn];
        }
}

// ---------------------------------------------------------------------------
// GEMM, no bias, bf16 output, per-batch TRANSPOSED store: CT[b][n][m] ushort.
// A rows are batch-major (512 rows per batch). Used for AW2 = attended @ W2.
// ---------------------------------------------------------------------------
__global__ __launch_bounds__(256) void gemm_T_bf16_kernel(
    const float* __restrict__ A, const float* __restrict__ B,
    unsigned short* __restrict__ CT, int M, int N, int K)
{
    __shared__ float As[16][68];
    __shared__ float Bs[16][68];
    __shared__ float Ts[64][65];
    const int tid = threadIdx.x;
    const int bm = blockIdx.x * 64;
    const int bn = blockIdx.y * 64;
    const int tx = tid & 15, ty = tid >> 4;
    const int ar = tid >> 2, ac = (tid & 3) * 4;
    const int br = tid >> 4, bc = (tid & 15) * 4;
    float acc[4][4] = {};

    for (int k0 = 0; k0 < K; k0 += 16) {
        float4 av = *(const float4*)(A + (size_t)(bm + ar) * K + k0 + ac);
        float4 bv = *(const float4*)(B + (size_t)(k0 + br) * N + bn + bc);
        As[ac + 0][ar] = av.x; As[ac + 1][ar] = av.y;
        As[ac + 2][ar] = av.z; As[ac + 3][ar] = av.w;
        *(float4*)(&Bs[br][bc]) = bv;
        __syncthreads();
#pragma unroll
        for (int kk = 0; kk < 16; ++kk) {
            float a0 = As[kk][ty*4+0], a1 = As[kk][ty*4+1];
            float a2 = As[kk][ty*4+2], a3 = As[kk][ty*4+3];
            float b0 = Bs[kk][tx*4+0], b1 = Bs[kk][tx*4+1];
            float b2 = Bs[kk][tx*4+2], b3 = Bs[kk][tx*4+3];
            acc[0][0]+=a0*b0; acc[0][1]+=a0*b1; acc[0][2]+=a0*b2; acc[0][3]+=a0*b3;
            acc[1][0]+=a1*b0; acc[1][1]+=a1*b1; acc[1][2]+=a1*b2; acc[1][3]+=a1*b3;
            acc[2][0]+=a2*b0; acc[2][1]+=a2*b1; acc[2][2]+=a2*b2; acc[2][3]+=a2*b3;
            acc[3][0]+=a3*b0; acc[3][1]+=a3*b1; acc[3][2]+=a3*b2; acc[3][3]+=a3*b3;
        }
        __syncthreads();
    }
#pragma unroll
    for (int i = 0; i < 4; ++i)
#pragma unroll
        for (int j = 0; j < 4; ++j)
            Ts[tx * 4 + j][ty * 4 + i] = acc[i][j];
    __syncthreads();
    const int jr = tid >> 2, ms2 = (tid & 3) * 16;
    const int b = bm >> 9, m0 = bm & 511;
    unsigned short* dst = CT + (size_t)b * ((size_t)N * 512)
                        + (size_t)(bn + jr) * 512 + m0 + ms2;
#pragma unroll
    for (int u = 0; u < 16; ++u) {
        unsigned ua = __float_as_uint(Ts[jr][ms2 + u]);
        ua = (ua + 0x7fffu + ((ua >> 16) & 1u)) >> 16;
        dst[u] = (unsigned short)ua;
    }
}

// ---------------------------------------------------------------------------
// Persistent scan: 128 blocks (8 per batch, XCD-clustered), 512 threads.
// Sync = self-validating tagged data words (tag = t in low 8 mantissa bits).
// No flags, no fences, no barriers: consumer lanes poll their own word.
// Two exchanges/step: p (64 words/block) and h (32 words/block).
// ---------------------------------------------------------------------------
__global__ __launch_bounds__(NTHR, 2) void rnn_persistent(
    const float* __restrict__ query_W, const float* __restrict__ query_b,
    const float* __restrict__ attn_W,  const float* __restrict__ lstm_U,
    const float* __restrict__ keys,    const float* __restrict__ pre,
    const unsigned short* __restrict__ aw2T,
    unsigned* pB, unsigned* hB,
    float* __restrict__ seq, float* __restrict__ hT, float* __restrict__ cT)
{
    const int bid = blockIdx.x;
    // XCD clustering heuristic (perf only): a batch's 8 blocks share bid%8
    const int b = (bid & 7) * 2 + (bid >> 6);
    const int g = (bid >> 3) & 7;
    const int tid = threadIdx.x;

    __shared__ __align__(16) float h_s[256];
    __shared__ __align__(16) float q_s[256];
    __shared__ __align__(16) float qp_s[8][256];
    __shared__ __align__(16) float aw_s[256];
    __shared__ __align__(16) float qb_s[256];
    __shared__ __align__(16) float pown_s[64];
    __shared__ __align__(16) float pgat_s[512];
    __shared__ __align__(16) float zp_s[8][128];
    __shared__ __align__(16) float z_s[128];
    __shared__ __align__(16) float red_s[8];

    // roles
    const int c64 = tid & 63, ms = tid >> 6;      // z-phase: 2 cols, m/k-slice ms
    const int j4  = tid & 63, kh = tid >> 6;      // q-phase: 4 cols, k-block kh
    const int mloc = tid >> 3, pp = tid & 7;      // scores: own m, j-octant pp

    const int cc0 = 2 * c64, cc1 = 2 * c64 + 1;
    const int col0 = ((cc0 >> 5) << 8) + g * 32 + (cc0 & 31);
    const int col1 = ((cc1 >> 5) << 8) + g * 32 + (cc1 & 31);

    // ---- t-invariant register state ----
    unsigned wq_r[4][16];    // Wq[kh*32+2i(+1)][j4*4+cc] bf16 pairs (pack along k)
#pragma unroll
    for (int cci = 0; cci < 4; ++cci) {
        int j = j4 * 4 + cci;
#pragma unroll
        for (int i = 0; i < 16; ++i)
            wq_r[cci][i] = pack_bf(query_W[(size_t)(kh * 32 + 2 * i) * 256 + j],
                                   query_W[(size_t)(kh * 32 + 2 * i + 1) * 256 + j]);
    }
    unsigned keys_r[16];     // keys[b][g*64+mloc][pp*32 + 2*jp(+1)], pre-rotated
    {
        const float* krow = keys + ((size_t)(b * MSLOTS + g * 64 + mloc)) * 256 + pp * 32;
#pragma unroll
        for (int i = 0; i < 16; ++i) {
            int jp = (i + pp * 2) & 15;
            keys_r[i] = pack_bf(krow[jp * 2], krow[jp * 2 + 1]);
        }
    }
    unsigned u_r[2][16];     // U[ms*32+2j(+1)][col] bf16 pairs (pack along k)
#pragma unroll
    for (int j = 0; j < 16; ++j) {
        u_r[0][j] = pack_bf(lstm_U[(size_t)(ms * 32 + 2 * j) * ZDIM + col0],
                            lstm_U[(size_t)(ms * 32 + 2 * j + 1) * ZDIM + col0]);
        u_r[1][j] = pack_bf(lstm_U[(size_t)(ms * 32 + 2 * j) * ZDIM + col1],
                            lstm_U[(size_t)(ms * 32 + 2 * j + 1) * ZDIM + col1]);
    }
    unsigned aw2_r[2][32];   // AW2[m = ms*64 + 2j(+1)][col] bf16 pairs (along m)
    {
        const unsigned* a0 = (const unsigned*)(aw2T + ((size_t)b * ZDIM + col0) * 512 + ms * 64);
        const unsigned* a1 = (const unsigned*)(aw2T + ((size_t)b * ZDIM + col1) * 512 + ms * 64);
#pragma unroll
        for (int j = 0; j < 32; ++j) { aw2_r[0][j] = a0[j]; aw2_r[1][j] = a1[j]; }
    }

    if (tid < 256) { aw_s[tid] = attn_W[tid]; qb_s[tid] = query_b[tid]; h_s[tid] = 0.0f; }
    float c_r = 0.0f;   // cell state for unit g*32 + tid (tid<32); block-local
    __syncthreads();

    const float* preb = pre + (size_t)b * TSTEPS * ZDIM;
    unsigned* pBb = pB + b * 512;
    unsigned* hBb = hB + b * 256;

    for (int t = 0; t < TSTEPS; ++t) {
        const unsigned tag = (unsigned)t;   // 0..127; never 0xAA/0xFF
        // hoisted pre load for this thread's z-reduce role (tid<128)
        float pre_r = 0.0f;
        if (tid < 128)
            pre_r = preb[(size_t)t * ZDIM + ((tid >> 5) << 8) + g * 32 + (tid & 31)];

        // ---- phase Q: q = h @ Wq + qb (redundant per block, from registers) ----
        {
            float qa0 = 0.f, qa1 = 0.f, qa2 = 0.f, qa3 = 0.f;
#pragma unroll
            for (int i = 0; i < 16; ++i) {
                float2 hv = *(const float2*)&h_s[kh * 32 + 2 * i];
                unsigned w0 = wq_r[0][i], w1 = wq_r[1][i], w2 = wq_r[2][i], w3 = wq_r[3][i];
                qa0 += hv.x * bf_lo(w0) + hv.y * bf_hi(w0);
                qa1 += hv.x * bf_lo(w1) + hv.y * bf_hi(w1);
                qa2 += hv.x * bf_lo(w2) + hv.y * bf_hi(w2);
                qa3 += hv.x * bf_lo(w3) + hv.y * bf_hi(w3);
            }
            *(float4*)&qp_s[kh][j4 * 4] = make_float4(qa0, qa1, qa2, qa3);
        }
        __syncthreads();
        if (tid < 256) {
            float acc = qb_s[tid];
#pragma unroll
            for (int i = 0; i < 8; ++i) acc += qp_s[i][tid];
            q_s[tid] = acc;
        }
        __syncthreads();

        // ---- phase S: scores + exp for own 64 m; publish tagged p ASAP ----
        {
            float sacc = 0.0f;
#pragma unroll
            for (int i = 0; i < 16; ++i) {
                int jp = (i + pp * 2) & 15;
                int j = pp * 32 + jp * 2;
                float2 qv = *(const float2*)&q_s[j];
                float2 av = *(const float2*)&aw_s[j];
                unsigned kw = keys_r[i];
                sacc += av.x * tanhf_fast(bf_lo(kw) + qv.x);
                sacc += av.y * tanhf_fast(bf_hi(kw) + qv.y);
            }
            sacc += __shfl_xor(sacc, 1);
            sacc += __shfl_xor(sacc, 2);
            sacc += __shfl_xor(sacc, 4);
            if (pp == 0) {
                float pv = __expf(sacc);                    // |s| <= ~13, no max-sub
                unsigned w = (__float_as_uint(pv) & 0xFFFFFF00u) | tag;
                pown_s[mloc] = __uint_as_float(w & 0xFFFFFF00u);
                st_agent_u(&pBb[g * 64 + mloc], w);         // data-is-flag publish
            }
        }

        // ---- z_h from registers (independent of p) — hides p propagation ----
        float zh0 = 0.f, zh1 = 0.f;
#pragma unroll
        for (int i = 0; i < 8; ++i) {
            float4 hv = *(const float4*)&h_s[ms * 32 + i * 4];
            unsigned w00 = u_r[0][2*i], w01 = u_r[0][2*i+1];
            unsigned w10 = u_r[1][2*i], w11 = u_r[1][2*i+1];
            zh0 += hv.x*bf_lo(w00) + hv.y*bf_hi(w00) + hv.z*bf_lo(w01) + hv.w*bf_hi(w01);
            zh1 += hv.x*bf_lo(w10) + hv.y*bf_hi(w10) + hv.z*bf_lo(w11) + hv.w*bf_hi(w11);
        }
        __syncthreads();   // pown_s visible for own-slice copy

        // ---- gather p (poll others' words; own slice from LDS) ----
        float pv;
        if ((tid >> 6) == g) pv = pown_s[tid & 63];
        else                 pv = poll_tagged(&pBb[tid], tag);
        pgat_s[tid] = pv;
        // denom reduction (wave, then cross-wave; redundant per thread)
        {
            float dv = pv;
            dv += __shfl_xor(dv, 1);  dv += __shfl_xor(dv, 2);  dv += __shfl_xor(dv, 4);
            dv += __shfl_xor(dv, 8);  dv += __shfl_xor(dv, 16); dv += __shfl_xor(dv, 32);
            if ((tid & 63) == 0) red_s[tid >> 6] = dv;
        }
        __syncthreads();
        float inv;
        {
            float tot = red_s[0] + red_s[1] + red_s[2] + red_s[3]
                      + red_s[4] + red_s[5] + red_s[6] + red_s[7];
            inv = 1.0f / tot;
        }

        // ---- phase Z: own 2 cols from registers ----
        {
            float zc0 = 0.f, zc1 = 0.f;
#pragma unroll
            for (int i = 0; i < 16; ++i) {
                float4 pvv = *(const float4*)&pgat_s[ms * 64 + i * 4];
                unsigned w00 = aw2_r[0][2*i], w01 = aw2_r[0][2*i+1];
                unsigned w10 = aw2_r[1][2*i], w11 = aw2_r[1][2*i+1];
                zc0 += pvv.x*bf_lo(w00) + pvv.y*bf_hi(w00) + pvv.z*bf_lo(w01) + pvv.w*bf_hi(w01);
                zc1 += pvv.x*bf_lo(w10) + pvv.y*bf_hi(w10) + pvv.z*bf_lo(w11) + pvv.w*bf_hi(w11);
            }
            *(float2*)&zp_s[ms][c64 * 2] = make_float2(zc0 * inv + zh0, zc1 * inv + zh1);
        }
        __syncthreads();
        if (tid < 128) {
            float z = pre_r;
#pragma unroll
            for (int i = 0; i < 8; ++i) z += zp_s[i][tid];
            z_s[tid] = z;
        }
        __syncthreads();

        // ---- gates + state for own 32 units; publish tagged h ----
        if (tid < 32) {
            float zi = z_s[tid], zf = z_s[32 + tid], zg = z_s[64 + tid], zo = z_s[96 + tid];
            float ig = sigmoidf_fast(zi);
            float fg = sigmoidf_fast(zf);
            float gg = tanhf_fast(zg);
            float og = sigmoidf_fast(zo);
            float cn = fg * c_r + ig * gg;
            float hn = og * tanhf_fast(cn);
            c_r = cn;
            unsigned w = (__float_as_uint(hn) & 0xFFFFFF00u) | tag;
            float hn_t = __uint_as_float(w & 0xFFFFFF00u);
            int u = g * 32 + tid;
            h_s[u] = hn_t;
            st_agent_u(&hBb[u], w);                         // data-is-flag publish
            seq[((size_t)b * TSTEPS + t) * UNITS + u] = hn_t;
            if (t == TSTEPS - 1) { hT[b * UNITS + u] = hn_t; cT[b * UNITS + u] = cn; }
        }

        // ---- gather h (poll others' words; own slice already in h_s) ----
        if (tid < 256 && (tid >> 5) != g)
            h_s[tid] = poll_tagged(&hBb[tid], tag);
        __syncthreads();
    }
}

// ---------------------------------------------------------------------------
extern "C" void kernel_launch(void* const* d_in, const int* in_sizes, int n_in,
                              void* d_out, int out_size, void* d_ws, size_t ws_size,
                              hipStream_t stream)
{
    (void)in_sizes; (void)n_in; (void)out_size; (void)ws_size;
    const float* inputs   = (const float*)d_in[0];
    const float* attended = (const float*)d_in[1];
    const float* key_W    = (const float*)d_in[2];
    const float* key_b    = (const float*)d_in[3];
    const float* query_W  = (const float*)d_in[4];
    const float* query_b  = (const float*)d_in[5];
    const float* attn_W   = (const float*)d_in[6];
    const float* lstm_W   = (const float*)d_in[8];
    const float* lstm_U   = (const float*)d_in[9];
    const float* lstm_b   = (const float*)d_in[10];
    // attn_b (d_in[7]) cancels in softmax — dropped.

    float* out = (float*)d_out;
    float* seq = out;
    float* hT  = out + (size_t)BATCH * TSTEPS * UNITS;
    float* cT  = hT + BATCH * UNITS;

    float* ws = (float*)d_ws;
    float* keys = ws;                                        // 2,097,152 f
    float* pre  = keys + 2097152;                            // 2,097,152 f
    unsigned short* aw2T = (unsigned short*)(pre + 2097152); // 16*1024*512 ushort
    unsigned* pB = (unsigned*)(aw2T + (size_t)16 * 1024 * 512); // 16*512 u32
    unsigned* hB = pB + BATCH * 512;                            // 16*256 u32

    // init comm words to tag 0xFF (never a valid step tag) — replay-safe
    hipMemsetAsync(pB, 0xFF, (size_t)BATCH * (512 + 256) * sizeof(unsigned), stream);

    // keys = attended @ key_W + key_b          (8192 x 256)
    gemm_bias_kernel<<<dim3(128, 4), 256, 0, stream>>>(
        attended, key_W, key_b, keys, 8192, 256, 256);
    // pre = inputs @ lstm_W[:256] + lstm_b     (2048 x 1024)
    gemm_bias_kernel<<<dim3(32, 16), 256, 0, stream>>>(
        inputs, lstm_W, lstm_b, pre, 2048, 1024, 256);
    // AW2^T (bf16) = (attended @ lstm_W[256:])^T per batch: [b][1024][512]
    gemm_T_bf16_kernel<<<dim3(128, 16), 256, 0, stream>>>(
        attended, lstm_W + (size_t)256 * ZDIM, aw2T, 8192, 1024, 256);

    rnn_persistent<<<dim3(NBLK), dim3(NTHR), 0, stream>>>(
        query_W, query_b, attn_W, lstm_U,
        keys, pre, aw2T, pB, hB, seq, hT, cT);
}